// Round 3
// baseline (7932.883 us; speedup 1.0000x reference)
//
#include <hip/hip_runtime.h>

#define NYc 256
#define NXc 256
#define NTc 256
#define NBc 2
#define NSRCc 2
#define NRECc 64
#define RR 8              // owned rows per block
#define HH 4              // halo rows each side
#define REGR 16           // region rows = RR + 2*HH
#define NBLKY 32          // blocks per batch
#define NBLKT 64          // total blocks
#define NGRP 128          // NT / 2 steps-per-group
#define DTc 0.0005f
#define INVD 0.2f

// workspace layout (float offsets)
#define COEF_OFF 0                                   // 1024 floats
#define FLAG_OFF 1024                                // 64 * 16 uints
#define SF_OFF   2048                                // [2][64][5][8][256]
#define SF_BLK   (5*8*256)
#define SX_OFF   (SF_OFF + 2*NBLKT*SF_BLK)           // [2][64][4][8][40]
#define SX_BLK   (4*8*40)
#define SY_OFF   (SX_OFF + 2*NBLKT*SX_BLK)           // [2][12][4][8][256]
#define SY_SLOTS 12
#define SY_BLK   (4*8*256)

#define LDS_BYTES (5*REGR*NXc*4)                     // 81920

__device__ __forceinline__ float ald(const float* p) {
  return __hip_atomic_load(p, __ATOMIC_RELAXED, __HIP_MEMORY_SCOPE_AGENT);
}
__device__ __forceinline__ void ast(float* p, float v) {
  __hip_atomic_store(p, v, __ATOMIC_RELAXED, __HIP_MEMORY_SCOPE_AGENT);
}
__device__ __forceinline__ int syslot(int b, int bi) {
  if (bi < 3)  return b*6 + bi;
  if (bi >= 29) return b*6 + 3 + (bi - 29);
  return -1;
}

__global__ __launch_bounds__(256) void setup_kernel(
    const float* __restrict__ lamb, const float* __restrict__ mu,
    const float* __restrict__ buoy, float* __restrict__ coef)
{
  __shared__ float red[256];
  const int tid = threadIdx.x;
  float m = 0.0f;
  for (int i = tid; i < NYc*NXc; i += 256)
    m = fmaxf(m, sqrtf((lamb[i] + 2.0f*mu[i]) * buoy[i]));
  red[tid] = m;
  __syncthreads();
  for (int s = 128; s > 0; s >>= 1) {
    if (tid < s) red[tid] = fmaxf(red[tid], red[tid+s]);
    __syncthreads();
  }
  const float maxv = red[0];

  const float i_f = (float)tid;
  const float w = 20.0f;
  float f1 = fminf(fmaxf((w - i_f) * (1.0f/w), 0.0f), 1.0f);
  float f2 = fminf(fmaxf((i_f - (256.0f - 1.0f - w)) * (1.0f/w), 0.0f), 1.0f);
  float frac = fmaxf(f1, f2);
  float sigma_max = 3.0f * maxv * 6.907755278982137f / (2.0f * w * 5.0f);
  float sigma = sigma_max * frac * frac;
  float alpha = 3.14159265358979323f * 25.0f * (1.0f - frac);
  float bc = expf(-(sigma + alpha) * 0.0005f);
  float ac = sigma / (sigma + alpha + 1e-9f) * (bc - 1.0f);
  coef[tid]       = ac;  // ay
  coef[256 + tid] = bc;  // by
  coef[512 + tid] = ac;  // ax
  coef[768 + tid] = bc;  // bx
}

#define LDSF(f,r,c) lds[(f)*(REGR*NXc) + (r)*NXc + (c)]

__global__ __launch_bounds__(512, 2) void elastic_halo(
    const float* __restrict__ lamb_g, const float* __restrict__ mu_g,
    const float* __restrict__ buoy_g, const float* __restrict__ amps,
    const int* __restrict__ src_loc, const int* __restrict__ rec_loc,
    float* __restrict__ ws, float* __restrict__ out)
{
  extern __shared__ float lds[];
  const int blk = blockIdx.x;
  const int b   = blk >> 5;
  const int bi  = blk & 31;
  const int tid = threadIdx.x;
  const int ty  = tid >> 8;          // 0/1
  const int tx  = tid & 255;
  const int y0  = bi * RR;
  const int reg_lo = y0 - HH;        // may be negative (bi==0)

  const float* coef = ws + COEF_OFF;
  unsigned int* flags = (unsigned int*)(ws + FLAG_OFF);

  const int txm = (tx > 0) ? tx-1 : 0;
  const int txp = (tx < 255) ? tx+1 : 255;
  const bool xm_ok = tx > 0, xp_ok = tx < 255;
  const int xc = (tx < 20) ? tx : ((tx >= 236) ? tx - 216 : -1);

  // ---- per-cell register state: k=0..7 -> local row r = ty + 2k ----
  float vy_[8], vx_[8], syy_[8], sxy_[8], sxx_[8];
  float m0_[8], m1_[8], m2_[8], m3_[8], m4_[8], m5_[8], m6_[8], m7_[8];
  float dtb_[8], lam_[8], mu_[8], l2m_[8], ay_[8], by_[8];

  #pragma unroll
  for (int k = 0; k < 8; ++k) {
    const int r = ty + 2*k;
    const int gy = reg_lo + r;
    float bu = 0.f, la = 0.f, mm = 0.f, a = 0.f, bb = 1.f;
    if (gy >= 0 && gy < NYc) {
      const int c2 = gy*NXc + tx;
      bu = buoy_g[c2]; la = lamb_g[c2]; mm = mu_g[c2];
      a = coef[gy]; bb = coef[256 + gy];
    }
    dtb_[k] = DTc * bu; lam_[k] = la; mu_[k] = mm; l2m_[k] = la + 2.f*mm;
    ay_[k] = a; by_[k] = bb;
    vy_[k] = vx_[k] = syy_[k] = sxy_[k] = sxx_[k] = 0.f;
    m0_[k]=m1_[k]=m2_[k]=m3_[k]=m4_[k]=m5_[k]=m6_[k]=m7_[k]=0.f;
  }
  const float axv = coef[512 + tx], bxv = coef[768 + tx];

  // ---- source slots (cells may be halo copies too) ----
  int sk0 = -1, sk1 = -1; int sb0 = 0, sb1 = 0;
  for (int i = 0; i < NBc*NSRCc; ++i) {
    const int sb = i >> 1;
    const int sy = src_loc[2*i], sx = src_loc[2*i+1];
    if (sb == b && sx == tx) {
      const int r = sy - reg_lo;
      if (r >= 0 && r < REGR && ((r - ty) & 1) == 0) {
        const int k = (r - ty) >> 1;
        if (sk0 < 0) { sk0 = k; sb0 = i*NTc; }
        else         { sk1 = k; sb1 = i*NTc; }
      }
    }
  }
  // ---- receiver slots (owned rows only) ----
  int rk0=-1, rk1=-1, rk2=-1, rk3=-1; int ro0=0, ro1=0, ro2=0, ro3=0;
  for (int i = 0; i < NBc*NRECc; ++i) {
    const int rb = i >> 6;
    const int ry = rec_loc[2*i], rx = rec_loc[2*i+1];
    if (rb == b && rx == tx && ry >= y0 && ry < y0 + RR) {
      const int r = ry - reg_lo;
      if (((r - ty) & 1) == 0) {
        const int k = (r - ty) >> 1;
        if      (rk0 < 0) { rk0 = k; ro0 = i*NTc; }
        else if (rk1 < 0) { rk1 = k; ro1 = i*NTc; }
        else if (rk2 < 0) { rk2 = k; ro2 = i*NTc; }
        else              { rk3 = k; ro3 = i*NTc; }
      }
    }
  }

  // ---- zero LDS ----
  for (int i = tid; i < 5*REGR*NXc; i += 512) lds[i] = 0.f;
  __syncthreads();

  const int mysy = syslot(b, bi);
  const int upsy = (bi > 0)  ? syslot(b, bi-1) : -1;
  const int dnsy = (bi < 31) ? syslot(b, bi+1) : -1;

  for (int g = 0; g < NGRP; ++g) {
    // ================= halo ingest =================
    if (g > 0) {
      if (tid == 0 && bi > 0) {
        const unsigned int* f = &flags[(blk-1)*16];
        while (__hip_atomic_load(f, __ATOMIC_RELAXED, __HIP_MEMORY_SCOPE_AGENT) < (unsigned)g) {}
      }
      if (tid == 1 && bi < 31) {
        const unsigned int* f = &flags[(blk+1)*16];
        while (__hip_atomic_load(f, __ATOMIC_RELAXED, __HIP_MEMORY_SCOPE_AGENT) < (unsigned)g) {}
      }
      __syncthreads();
      const int par = (g - 1) & 1;
      if (bi > 0) {
        const float* sf = ws + SF_OFF + ((size_t)par*NBLKT + (blk-1))*SF_BLK;
        const float* sx = ws + SX_OFF + ((size_t)par*NBLKT + (blk-1))*SX_BLK;
        const float* sy = (upsy >= 0) ? ws + SY_OFF + ((size_t)par*SY_SLOTS + upsy)*SY_BLK : nullptr;
        #pragma unroll
        for (int k = 0; k < 2; ++k) {
          const int r = ty + 2*k;
          const int j = (reg_lo + r) - (y0 - 8);   // in [4,8)
          float v;
          v = ald(sf + (0*8+j)*256 + tx); vy_[k]  = v; LDSF(0,r,tx) = v;
          v = ald(sf + (1*8+j)*256 + tx); vx_[k]  = v; LDSF(1,r,tx) = v;
          v = ald(sf + (2*8+j)*256 + tx); syy_[k] = v; LDSF(2,r,tx) = v;
          v = ald(sf + (3*8+j)*256 + tx); sxy_[k] = v; LDSF(3,r,tx) = v;
          v = ald(sf + (4*8+j)*256 + tx); sxx_[k] = v; LDSF(4,r,tx) = v;
          if (xc >= 0) {
            m1_[k] = ald(sx + (0*8+j)*40 + xc);
            m3_[k] = ald(sx + (1*8+j)*40 + xc);
            m5_[k] = ald(sx + (2*8+j)*40 + xc);
            m6_[k] = ald(sx + (3*8+j)*40 + xc);
          }
          if (sy) {
            m0_[k] = ald(sy + (0*8+j)*256 + tx);
            m2_[k] = ald(sy + (1*8+j)*256 + tx);
            m4_[k] = ald(sy + (2*8+j)*256 + tx);
            m7_[k] = ald(sy + (3*8+j)*256 + tx);
          }
        }
      }
      if (bi < 31) {
        const float* sf = ws + SF_OFF + ((size_t)par*NBLKT + (blk+1))*SF_BLK;
        const float* sx = ws + SX_OFF + ((size_t)par*NBLKT + (blk+1))*SX_BLK;
        const float* sy = (dnsy >= 0) ? ws + SY_OFF + ((size_t)par*SY_SLOTS + dnsy)*SY_BLK : nullptr;
        #pragma unroll
        for (int k = 6; k < 8; ++k) {
          const int r = ty + 2*k;
          const int j = (reg_lo + r) - (y0 + 8);   // in [0,4)
          float v;
          v = ald(sf + (0*8+j)*256 + tx); vy_[k]  = v; LDSF(0,r,tx) = v;
          v = ald(sf + (1*8+j)*256 + tx); vx_[k]  = v; LDSF(1,r,tx) = v;
          v = ald(sf + (2*8+j)*256 + tx); syy_[k] = v; LDSF(2,r,tx) = v;
          v = ald(sf + (3*8+j)*256 + tx); sxy_[k] = v; LDSF(3,r,tx) = v;
          v = ald(sf + (4*8+j)*256 + tx); sxx_[k] = v; LDSF(4,r,tx) = v;
          if (xc >= 0) {
            m1_[k] = ald(sx + (0*8+j)*40 + xc);
            m3_[k] = ald(sx + (1*8+j)*40 + xc);
            m5_[k] = ald(sx + (2*8+j)*40 + xc);
            m6_[k] = ald(sx + (3*8+j)*40 + xc);
          }
          if (sy) {
            m0_[k] = ald(sy + (0*8+j)*256 + tx);
            m2_[k] = ald(sy + (1*8+j)*256 + tx);
            m4_[k] = ald(sy + (2*8+j)*256 + tx);
            m7_[k] = ald(sy + (3*8+j)*256 + tx);
          }
        }
      }
      __syncthreads();
    }

    // ================= 2 timesteps (4 phases) =================
    #pragma unroll
    for (int s = 0; s < 2; ++s) {
      const int t = 2*g + s;
      // ---- phase A (velocity), p = 2s ----
      {
        const int p = 2*s;
        const int wlo = max(0, y0 - 3 + p);
        const int whi = min(NYc, y0 + RR + 3 - p);
        #pragma unroll
        for (int k = 0; k < 8; ++k) {
          const int r = ty + 2*k;
          const int gy = reg_lo + r;
          if (gy < wlo || gy >= whi) continue;
          float v, d;
          v = LDSF(2, r-1, tx);
          d = (gy > 0) ? (syy_[k] - v) * INVD : 0.f;
          m0_[k] = by_[k]*m0_[k] + ay_[k]*d;
          float t1 = d + m0_[k];
          v = LDSF(3, r, txm);
          d = xm_ok ? (sxy_[k] - v) * INVD : 0.f;
          m1_[k] = bxv*m1_[k] + axv*d;
          float t2 = d + m1_[k];
          vy_[k] += dtb_[k] * (t1 + t2);
          v = LDSF(3, r+1, tx);
          d = (gy < NYc-1) ? (v - sxy_[k]) * INVD : 0.f;
          m2_[k] = by_[k]*m2_[k] + ay_[k]*d;
          float t3 = d + m2_[k];
          v = LDSF(4, r, txp);
          d = xp_ok ? (v - sxx_[k]) * INVD : 0.f;
          m3_[k] = bxv*m3_[k] + axv*d;
          float t4 = d + m3_[k];
          vx_[k] += dtb_[k] * (t3 + t4);
          if (k == sk0) vy_[k] += amps[sb0 + t] * dtb_[k];
          if (k == sk1) vy_[k] += amps[sb1 + t] * dtb_[k];
          LDSF(0, r, tx) = vy_[k];
          LDSF(1, r, tx) = vx_[k];
          if (k == rk0) out[ro0 + t] = vy_[k];
          if (k == rk1) out[ro1 + t] = vy_[k];
          if (k == rk2) out[ro2 + t] = vy_[k];
          if (k == rk3) out[ro3 + t] = vy_[k];
        }
      }
      __syncthreads();
      // ---- phase B (stress), p = 2s+1 ----
      {
        const int p = 2*s + 1;
        const int wlo = max(0, y0 - 3 + p);
        const int whi = min(NYc, y0 + RR + 3 - p);
        #pragma unroll
        for (int k = 0; k < 8; ++k) {
          const int r = ty + 2*k;
          const int gy = reg_lo + r;
          if (gy < wlo || gy >= whi) continue;
          float v, d;
          v = LDSF(0, r+1, tx);
          d = (gy < NYc-1) ? (v - vy_[k]) * INVD : 0.f;
          m4_[k] = by_[k]*m4_[k] + ay_[k]*d;
          float t5 = d + m4_[k];
          v = LDSF(1, r, txm);
          d = xm_ok ? (vx_[k] - v) * INVD : 0.f;
          m5_[k] = bxv*m5_[k] + axv*d;
          float t6 = d + m5_[k];
          syy_[k] += DTc * (l2m_[k]*t5 + lam_[k]*t6);
          sxx_[k] += DTc * (lam_[k]*t5 + l2m_[k]*t6);
          v = LDSF(0, r, txm);
          d = xm_ok ? (vy_[k] - v) * INVD : 0.f;
          m6_[k] = bxv*m6_[k] + axv*d;
          float t7 = d + m6_[k];
          v = LDSF(1, r-1, tx);
          d = (gy > 0) ? (vx_[k] - v) * INVD : 0.f;
          m7_[k] = by_[k]*m7_[k] + ay_[k]*d;
          float t8 = d + m7_[k];
          sxy_[k] += DTc * mu_[k] * (t7 + t8);
          LDSF(2, r, tx) = syy_[k];
          LDSF(3, r, tx) = sxy_[k];
          LDSF(4, r, tx) = sxx_[k];
        }
      }
      __syncthreads();
    }

    // ================= staging write + flag =================
    if (g < NGRP - 1) {
      const int par = g & 1;
      float* sf = ws + SF_OFF + ((size_t)par*NBLKT + blk)*SF_BLK;
      float* sx = ws + SX_OFF + ((size_t)par*NBLKT + blk)*SX_BLK;
      float* sy = (mysy >= 0) ? ws + SY_OFF + ((size_t)par*SY_SLOTS + mysy)*SY_BLK : nullptr;
      #pragma unroll
      for (int k = 2; k < 6; ++k) {
        const int r = ty + 2*k;
        const int j = r - HH;                    // gy - y0, in [0,8)
        ast(sf + (0*8+j)*256 + tx, vy_[k]);
        ast(sf + (1*8+j)*256 + tx, vx_[k]);
        ast(sf + (2*8+j)*256 + tx, syy_[k]);
        ast(sf + (3*8+j)*256 + tx, sxy_[k]);
        ast(sf + (4*8+j)*256 + tx, sxx_[k]);
        if (xc >= 0) {
          ast(sx + (0*8+j)*40 + xc, m1_[k]);
          ast(sx + (1*8+j)*40 + xc, m3_[k]);
          ast(sx + (2*8+j)*40 + xc, m5_[k]);
          ast(sx + (3*8+j)*40 + xc, m6_[k]);
        }
        if (sy) {
          ast(sy + (0*8+j)*256 + tx, m0_[k]);
          ast(sy + (1*8+j)*256 + tx, m2_[k]);
          ast(sy + (2*8+j)*256 + tx, m4_[k]);
          ast(sy + (3*8+j)*256 + tx, m7_[k]);
        }
      }
      __syncthreads();   // all threads' staging stores drained (vmcnt) before flag
      if (tid == 0)
        __hip_atomic_store(&flags[blk*16], (unsigned)(g+1),
                           __ATOMIC_RELEASE, __HIP_MEMORY_SCOPE_AGENT);
    }
  }
}

extern "C" void kernel_launch(void* const* d_in, const int* in_sizes, int n_in,
                              void* d_out, int out_size, void* d_ws, size_t ws_size,
                              hipStream_t stream) {
  const float* lamb    = (const float*)d_in[0];
  const float* mu      = (const float*)d_in[1];
  const float* buoy    = (const float*)d_in[2];
  const float* amps    = (const float*)d_in[3];
  const int*   src_loc = (const int*)d_in[4];
  const int*   rec_loc = (const int*)d_in[5];
  float* out = (float*)d_out;
  float* ws  = (float*)d_ws;

  // flags must start at 0 (monotonic within one launch)
  hipMemsetAsync(ws + FLAG_OFF, 0, NBLKT*16*sizeof(unsigned int), stream);

  hipLaunchKernelGGL(setup_kernel, dim3(1), dim3(256), 0, stream,
                     lamb, mu, buoy, ws + COEF_OFF);

  static int shmem_set = 0;
  if (!shmem_set) {
    (void)hipFuncSetAttribute((const void*)elastic_halo,
                              hipFuncAttributeMaxDynamicSharedMemorySize,
                              LDS_BYTES);
    shmem_set = 1;
  }

  void* args[] = { (void*)&lamb, (void*)&mu, (void*)&buoy, (void*)&amps,
                   (void*)&src_loc, (void*)&rec_loc, (void*)&ws, (void*)&out };
  hipLaunchCooperativeKernel((void*)elastic_halo, dim3(NBLKT), dim3(512),
                             args, LDS_BYTES, stream);
}

// Round 4
// 1733.732 us; speedup vs baseline: 4.5756x; 4.5756x over previous
//
#include <hip/hip_runtime.h>

#define NYq 256
#define NXq 256
#define NTq 256
#define NBq 2
#define NSRCq 2
#define NRECq 64
#define NBLKT 256            // 128 per batch, 2 rows each
#define DTc 0.0005f
#define INVD 0.2f

// workspace layout (float offsets)
#define COEF_OFF 0                         // 1024 floats
#define FLAG_OFF 1024                      // 256*16 uints (16KB)
#define STAGE_OFF (1024 + 4096)            // [2 parity][256 blk][3 f][2 rows][256]
#define STAGE_BLK (3*2*256)

__device__ __forceinline__ float ald(const float* p) {
  return __hip_atomic_load(p, __ATOMIC_RELAXED, __HIP_MEMORY_SCOPE_AGENT);
}
__device__ __forceinline__ void ast(float* p, float v) {
  __hip_atomic_store(p, v, __ATOMIC_RELAXED, __HIP_MEMORY_SCOPE_AGENT);
}

__global__ __launch_bounds__(256) void setup_kernel(
    const float* __restrict__ lamb, const float* __restrict__ mu,
    const float* __restrict__ buoy, float* __restrict__ coef)
{
  __shared__ float red[256];
  const int tid = threadIdx.x;
  float m = 0.0f;
  for (int i = tid; i < NYq*NXq; i += 256)
    m = fmaxf(m, sqrtf((lamb[i] + 2.0f*mu[i]) * buoy[i]));
  red[tid] = m;
  __syncthreads();
  for (int s = 128; s > 0; s >>= 1) {
    if (tid < s) red[tid] = fmaxf(red[tid], red[tid+s]);
    __syncthreads();
  }
  const float maxv = red[0];

  const float i_f = (float)tid;
  const float w = 20.0f;
  float f1 = fminf(fmaxf((w - i_f) * (1.0f/w), 0.0f), 1.0f);
  float f2 = fminf(fmaxf((i_f - (256.0f - 1.0f - w)) * (1.0f/w), 0.0f), 1.0f);
  float frac = fmaxf(f1, f2);
  float sigma_max = 3.0f * maxv * 6.907755278982137f / (2.0f * w * 5.0f);
  float sigma = sigma_max * frac * frac;
  float alpha = 3.14159265358979323f * 25.0f * (1.0f - frac);
  float bc = expf(-(sigma + alpha) * 0.0005f);
  float ac = sigma / (sigma + alpha + 1e-9f) * (bc - 1.0f);
  coef[tid]       = ac;  // ay
  coef[256 + tid] = bc;  // by
  coef[512 + tid] = ac;  // ax
  coef[768 + tid] = bc;  // bx
}

__global__ __launch_bounds__(512) void elastic_fused(
    const float* __restrict__ lamb_g, const float* __restrict__ mu_g,
    const float* __restrict__ buoy_g, const float* __restrict__ amps,
    const int* __restrict__ src_loc, const int* __restrict__ rec_loc,
    float* __restrict__ ws, float* __restrict__ out)
{
  // LDS: stress rows gy = lo-2 .. lo+3 ; velocity rows gy = lo-1 .. lo+2
  __shared__ float S[3][6][NXq];   // syy, sxy, sxx
  __shared__ float V[2][4][NXq];   // vy, vx

  const int blk = blockIdx.x;           // 0..255
  const int b   = blk >> 7;
  const int bi  = blk & 127;
  const int tid = threadIdx.x;
  const int ty  = tid >> 8;             // 0/1
  const int tx  = tid & 255;
  const int lo  = bi << 1;              // first owned row

  const float* coef = ws + COEF_OFF;
  unsigned int* flags = (unsigned int*)(ws + FLAG_OFF);
  float* stage = ws + STAGE_OFF;

  const int txm = (tx > 0) ? tx-1 : 0;
  const int txp = (tx < 255) ? tx+1 : 255;
  const bool xm_ok = tx > 0, xp_ok = tx < 255;
  const float axv = coef[512 + tx], bxv = coef[768 + tx];

  // ---- velocity cells: k=0,1 -> local region row r = ty+2k, gy = lo-1+r ----
  float vy_[2], vx_[2], m_syyy[2], m_sxyx[2], m_sxyy[2], m_sxxx[2];
  float dtb_[2], ayv_[2], byv_[2];
  #pragma unroll
  for (int k = 0; k < 2; ++k) {
    const int gy = lo - 1 + ty + 2*k;
    float bu = 0.f, a = 0.f, bb = 1.f;
    if (gy >= 0 && gy < NYq) {
      bu = buoy_g[gy*NXq + tx];
      a = coef[gy]; bb = coef[256 + gy];
    }
    dtb_[k] = DTc * bu; ayv_[k] = a; byv_[k] = bb;
    vy_[k] = vx_[k] = 0.f;
    m_syyy[k] = m_sxyx[k] = m_sxyy[k] = m_sxxx[k] = 0.f;
  }

  // ---- stress cell: gy_s = lo + ty (always in-grid) ----
  const int gy_s = lo + ty;
  const float lam = lamb_g[gy_s*NXq + tx];
  const float muv = mu_g[gy_s*NXq + tx];
  const float l2m = lam + 2.f*muv;
  const float ays = coef[gy_s], bys = coef[256 + gy_s];
  float syy = 0.f, sxy = 0.f, sxx = 0.f;
  float mvyy = 0.f, mvxx = 0.f, mvyx = 0.f, mvxy = 0.f;

  // ---- source slots over the 4-row velocity region ----
  int sk0 = -1, sk1 = -1; int sb0 = 0, sb1 = 0;
  for (int i = 0; i < NBq*NSRCq; ++i) {
    const int sb = i >> 1;
    const int sy = src_loc[2*i], sx = src_loc[2*i+1];
    if (sb == b && sx == tx) {
      const int rr = sy - (lo - 1);
      if (rr >= 0 && rr < 4 && ((rr - ty) & 1) == 0) {
        const int k = (rr - ty) >> 1;
        if (sk0 < 0) { sk0 = k; sb0 = i*NTq; }
        else         { sk1 = k; sb1 = i*NTq; }
      }
    }
  }

  // ---- receiver masks for this thread's OWN velocity cell ----
  // ty=0 -> own cell k=1 (gy=lo+1); ty=1 -> own cell k=0 (gy=lo)
  const int gy_own = lo + 1 - ty;
  unsigned long long rm0 = 0ull, rm1 = 0ull;
  for (int i = 0; i < NBq*NRECq; ++i) {
    const int rb = i >> 6;
    const int ry = rec_loc[2*i], rx = rec_loc[2*i+1];
    if (rb == b && ry == gy_own && rx == tx) {
      if (i < 64) rm0 |= 1ull << i; else rm1 |= 1ull << (i-64);
    }
  }
  const bool isrec = (rm0 | rm1) != 0ull;

  // ---- zero LDS ----
  {
    float* p1 = &S[0][0][0];
    for (int i = tid; i < 3*6*NXq; i += 512) p1[i] = 0.f;
    float* p2 = &V[0][0][0];
    for (int i = tid; i < 2*4*NXq; i += 512) p2[i] = 0.f;
  }
  __syncthreads();

  for (int t = 0; t < NTq; ++t) {
    // ============ wait + halo ingest (stress rows of t-1) ============
    if (t > 0) {
      if (tid == 0 && bi > 0) {
        const unsigned int* f = &flags[(blk-1)*16];
        while (__hip_atomic_load(f, __ATOMIC_RELAXED, __HIP_MEMORY_SCOPE_AGENT) < (unsigned)t) {}
      }
      if (tid == 64 && bi < 127) {
        const unsigned int* f = &flags[(blk+1)*16];
        while (__hip_atomic_load(f, __ATOMIC_RELAXED, __HIP_MEMORY_SCOPE_AGENT) < (unsigned)t) {}
      }
      __syncthreads();
      const int par = (t - 1) & 1;
      if (bi > 0) {          // rows gy = lo-2+ty  -> S row ty
        const float* sp = stage + ((size_t)par*NBLKT + (blk-1))*STAGE_BLK;
        #pragma unroll
        for (int f = 0; f < 3; ++f)
          S[f][ty][tx] = ald(sp + (f*2 + ty)*NXq + tx);
      }
      if (bi < 127) {        // rows gy = lo+2+ty  -> S row 4+ty
        const float* sp = stage + ((size_t)par*NBLKT + (blk+1))*STAGE_BLK;
        #pragma unroll
        for (int f = 0; f < 3; ++f)
          S[f][4+ty][tx] = ald(sp + (f*2 + ty)*NXq + tx);
      }
      __syncthreads();
    }

    // ============ phase A: velocity on 4 region rows ============
    #pragma unroll
    for (int k = 0; k < 2; ++k) {
      const int r = ty + 2*k;
      const int gy = lo - 1 + r;
      if (gy >= 0 && gy < NYq) {
        const int sr = r + 1;                 // S row for gy
        float d;
        d = (gy > 0) ? (S[0][sr][tx] - S[0][sr-1][tx]) * INVD : 0.f;   // dby(syy)
        m_syyy[k] = byv_[k]*m_syyy[k] + ayv_[k]*d;
        const float t1 = d + m_syyy[k];
        d = xm_ok ? (S[1][sr][tx] - S[1][sr][txm]) * INVD : 0.f;       // dbx(sxy)
        m_sxyx[k] = bxv*m_sxyx[k] + axv*d;
        const float t2 = d + m_sxyx[k];
        vy_[k] += dtb_[k] * (t1 + t2);
        d = (gy < NYq-1) ? (S[1][sr+1][tx] - S[1][sr][tx]) * INVD : 0.f; // dfy(sxy)
        m_sxyy[k] = byv_[k]*m_sxyy[k] + ayv_[k]*d;
        const float t3 = d + m_sxyy[k];
        d = xp_ok ? (S[2][sr][txp] - S[2][sr][tx]) * INVD : 0.f;       // dfx(sxx)
        m_sxxx[k] = bxv*m_sxxx[k] + axv*d;
        const float t4 = d + m_sxxx[k];
        vx_[k] += dtb_[k] * (t3 + t4);
        if (k == sk0) vy_[k] += amps[sb0 + t] * dtb_[k];
        if (k == sk1) vy_[k] += amps[sb1 + t] * dtb_[k];
        V[0][r][tx] = vy_[k];
        V[1][r][tx] = vx_[k];
      }
    }
    // recording (own cell, post-injection)
    if (isrec) {
      const float v = (ty == 0) ? vy_[1] : vy_[0];
      unsigned long long m0 = rm0;
      while (m0) { const int i = __ffsll((long long)m0) - 1; m0 &= m0 - 1; out[i*NTq + t] = v; }
      unsigned long long m1 = rm1;
      while (m1) { const int i = __ffsll((long long)m1) - 1; m1 &= m1 - 1; out[(i+64)*NTq + t] = v; }
    }
    __syncthreads();

    // ============ phase B: stress on own row ============
    {
      const int vr = ty + 1;                  // V row for gy_s
      float d;
      d = (gy_s < NYq-1) ? (V[0][vr+1][tx] - V[0][vr][tx]) * INVD : 0.f; // dfy(vy)
      mvyy = bys*mvyy + ays*d;
      const float t5 = d + mvyy;
      d = xm_ok ? (V[1][vr][tx] - V[1][vr][txm]) * INVD : 0.f;          // dbx(vx)
      mvxx = bxv*mvxx + axv*d;
      const float t6 = d + mvxx;
      syy += DTc * (l2m*t5 + lam*t6);
      sxx += DTc * (lam*t5 + l2m*t6);
      d = xm_ok ? (V[0][vr][tx] - V[0][vr][txm]) * INVD : 0.f;          // dbx(vy)
      mvyx = bxv*mvyx + axv*d;
      const float t7 = d + mvyx;
      d = (gy_s > 0) ? (V[1][vr][tx] - V[1][vr-1][tx]) * INVD : 0.f;    // dby(vx)
      mvxy = bys*mvxy + ays*d;
      const float t8 = d + mvxy;
      sxy += DTc * muv * (t7 + t8);

      S[0][ty+2][tx] = syy;
      S[1][ty+2][tx] = sxy;
      S[2][ty+2][tx] = sxx;

      // stage own stress rows for neighbors (parity t&1)
      float* sp = stage + ((size_t)(t & 1)*NBLKT + blk)*STAGE_BLK + ty*NXq + tx;
      ast(sp + 0*2*NXq, syy);
      ast(sp + 1*2*NXq, sxy);
      ast(sp + 2*2*NXq, sxx);
    }
    __syncthreads();   // LDS visible + all staging stores drained (vmcnt)
    if (tid == 0)
      __hip_atomic_store(&flags[blk*16], (unsigned)(t+1),
                         __ATOMIC_RELEASE, __HIP_MEMORY_SCOPE_AGENT);
  }
}

extern "C" void kernel_launch(void* const* d_in, const int* in_sizes, int n_in,
                              void* d_out, int out_size, void* d_ws, size_t ws_size,
                              hipStream_t stream) {
  const float* lamb    = (const float*)d_in[0];
  const float* mu      = (const float*)d_in[1];
  const float* buoy    = (const float*)d_in[2];
  const float* amps    = (const float*)d_in[3];
  const int*   src_loc = (const int*)d_in[4];
  const int*   rec_loc = (const int*)d_in[5];
  float* out = (float*)d_out;
  float* ws  = (float*)d_ws;

  // flags must start at 0 (monotonic within one launch)
  hipMemsetAsync(ws + FLAG_OFF, 0, NBLKT*16*sizeof(unsigned int), stream);

  hipLaunchKernelGGL(setup_kernel, dim3(1), dim3(256), 0, stream,
                     lamb, mu, buoy, ws + COEF_OFF);

  void* args[] = { (void*)&lamb, (void*)&mu, (void*)&buoy, (void*)&amps,
                   (void*)&src_loc, (void*)&rec_loc, (void*)&ws, (void*)&out };
  hipLaunchCooperativeKernel((void*)elastic_fused, dim3(NBLKT), dim3(512),
                             args, 0, stream);
}

// Round 5
// 762.812 us; speedup vs baseline: 10.3995x; 2.2728x over previous
//
#include <hip/hip_runtime.h>

#define NYr 256
#define NXr 256
#define NTr 256
#define NBr 2
#define NSRCr 2
#define NRECr 64
#define NBLK 128           // 2 batches x 64 blocks, 4 rows each
#define DTv 0.0005f
#define INVD 0.2f

// workspace layout (float offsets)
#define COEF_OFF 0                     // 1024 floats
#define FLAG_OFF 1024                  // 128*16 uints = 8KB = 2048 float slots
#define STAGE_OFF 3072                 // [2 parity][128 blk][3 f][4 rows][256]
#define STAGE_BLK (3*4*256)

__device__ __forceinline__ float ald(const float* p) {
  return __hip_atomic_load(p, __ATOMIC_RELAXED, __HIP_MEMORY_SCOPE_AGENT);
}
__device__ __forceinline__ void ast(float* p, float v) {
  __hip_atomic_store(p, v, __ATOMIC_RELAXED, __HIP_MEMORY_SCOPE_AGENT);
}

__global__ __launch_bounds__(256) void setup_kernel(
    const float* __restrict__ lamb, const float* __restrict__ mu,
    const float* __restrict__ buoy, float* __restrict__ coef)
{
  __shared__ float red[256];
  const int tid = threadIdx.x;
  float m = 0.0f;
  for (int i = tid; i < NYr*NXr; i += 256)
    m = fmaxf(m, sqrtf((lamb[i] + 2.0f*mu[i]) * buoy[i]));
  red[tid] = m;
  __syncthreads();
  for (int s = 128; s > 0; s >>= 1) {
    if (tid < s) red[tid] = fmaxf(red[tid], red[tid+s]);
    __syncthreads();
  }
  const float maxv = red[0];

  const float i_f = (float)tid;
  const float w = 20.0f;
  float f1 = fminf(fmaxf((w - i_f) * (1.0f/w), 0.0f), 1.0f);
  float f2 = fminf(fmaxf((i_f - (256.0f - 1.0f - w)) * (1.0f/w), 0.0f), 1.0f);
  float frac = fmaxf(f1, f2);
  float sigma_max = 3.0f * maxv * 6.907755278982137f / (2.0f * w * 5.0f);
  float sigma = sigma_max * frac * frac;
  float alpha = 3.14159265358979323f * 25.0f * (1.0f - frac);
  float bc = expf(-(sigma + alpha) * 0.0005f);
  float ac = sigma / (sigma + alpha + 1e-9f) * (bc - 1.0f);
  coef[tid]       = ac;  // ay
  coef[256 + tid] = bc;  // by
  coef[512 + tid] = ac;  // ax
  coef[768 + tid] = bc;  // bx
}

__global__ __launch_bounds__(512) void elastic4(
    const float* __restrict__ lamb_g, const float* __restrict__ mu_g,
    const float* __restrict__ buoy_g, const float* __restrict__ amps,
    const int* __restrict__ src_loc, const int* __restrict__ rec_loc,
    float* __restrict__ ws, float* __restrict__ out)
{
  __shared__ float S[3][4][NXr];   // own stress rows gy = lo..lo+3
  __shared__ float V[2][6][NXr];   // velocity rows gy = lo-1..lo+4

  const int blk = blockIdx.x;
  const int b = blk >> 6, bi = blk & 63;
  const int tid = threadIdx.x;
  const int ty = tid >> 8, tx = tid & 255;   // ty is wave-uniform
  const int lo = bi << 2;
  const bool hasUp = bi > 0, hasDn = bi < 63;

  const float* coef = ws + COEF_OFF;
  unsigned int* flags = (unsigned int*)(ws + FLAG_OFF);
  float* stage = ws + STAGE_OFF;

  const int txm = tx ? tx-1 : 0;
  const int txp = (tx < 255) ? tx+1 : 255;
  const bool xm_ok = tx > 0, xp_ok = tx < 255;
  const float axv = coef[512+tx], bxv = coef[768+tx];

  // ---- velocity cells k=0..2: gy = lo-1+ty+2k ----
  float vy_[3], vx_[3], myy[3], myx[3], mxyy[3], mxx[3];
  float dtb_[3], ayv[3], byv[3];
  #pragma unroll
  for (int k = 0; k < 3; ++k) {
    const int gy = lo - 1 + ty + 2*k;
    const bool ok = (gy >= 0) && (gy < NYr);
    const int gyc = ok ? gy : 0;
    dtb_[k] = ok ? DTv * buoy_g[gyc*NXr + tx] : 0.f;
    ayv[k]  = ok ? coef[gyc] : 0.f;
    byv[k]  = ok ? coef[256 + gyc] : 1.f;
    vy_[k] = vx_[k] = myy[k] = myx[k] = mxyy[k] = mxx[k] = 0.f;
  }
  // ---- stress cells j=0,1: gy = lo+ty+2j (always in-grid) ----
  float syy_[2], sxy_[2], sxx_[2], mvyy[2], mvxx[2], mvyx[2], mvxy[2];
  float lamv[2], muv[2], l2mv[2], ays[2], bys[2];
  #pragma unroll
  for (int j = 0; j < 2; ++j) {
    const int gy = lo + ty + 2*j;
    lamv[j] = lamb_g[gy*NXr + tx]; muv[j] = mu_g[gy*NXr + tx];
    l2mv[j] = lamv[j] + 2.f*muv[j];
    ays[j] = coef[gy]; bys[j] = coef[256 + gy];
    syy_[j] = sxy_[j] = sxx_[j] = 0.f;
    mvyy[j] = mvxx[j] = mvyx[j] = mvxy[j] = 0.f;
  }

  // ---- sources (halo replicas inject too, consistently) ----
  int sk0 = -1, sk1 = -1; int so0 = 0, so1 = 0;
  for (int i = 0; i < NBr*NSRCr; ++i) {
    const int sb = i >> 1, sy = src_loc[2*i], sx = src_loc[2*i+1];
    if (sb == b && sx == tx) {
      #pragma unroll
      for (int k = 0; k < 3; ++k) {
        const int gy = lo - 1 + ty + 2*k;
        if (gy == sy) { if (sk0 < 0) { sk0 = k; so0 = i*NTr; } else { sk1 = k; so1 = i*NTr; } }
      }
    }
  }
  // ---- receivers: own cells only (rows lo..lo+3, unique owner) ----
  const int gyA = ty ? lo     : lo + 1;   // cell A: k = ty?0:1
  const int gyB = ty ? lo + 2 : lo + 3;   // cell B: k = ty?1:2
  unsigned long long mA0=0, mA1=0, mB0=0, mB1=0;
  for (int i = 0; i < NBr*NRECr; ++i) {
    const int rb = i >> 6, ry = rec_loc[2*i], rx = rec_loc[2*i+1];
    if (rb == b && rx == tx) {
      if (ry == gyA) { if (i < 64) mA0 |= 1ull<<i; else mA1 |= 1ull<<(i-64); }
      if (ry == gyB) { if (i < 64) mB0 |= 1ull<<i; else mB1 |= 1ull<<(i-64); }
    }
  }
  const bool recA = (mA0|mA1) != 0ull, recB = (mB0|mB1) != 0ull;

  // ---- zero LDS ----
  { float* p = &S[0][0][0]; for (int i = tid; i < 3*4*NXr; i += 512) p[i] = 0.f;
    float* q = &V[0][0][0]; for (int i = tid; i < 2*6*NXr; i += 512) q[i] = 0.f; }
  __syncthreads();

  for (int t = 0; t < NTr; ++t) {
    // amps prefetch (issued early, used later in A phases)
    float a0 = 0.f, a1 = 0.f;
    if (sk0 >= 0) a0 = amps[so0 + t];
    if (sk1 >= 0) a1 = amps[so1 + t];

    // ========== A-interior: k=1, gy = lo+1+ty (no remote deps) ==========
    {
      const int sr = 1 + ty;
      float d, u1, u2, u3, u4;
      d = (S[0][sr][tx] - S[0][sr-1][tx]) * INVD;            // gy>0 always
      myy[1] = byv[1]*myy[1] + ayv[1]*d; u1 = d + myy[1];
      d = xm_ok ? (S[1][sr][tx] - S[1][sr][txm]) * INVD : 0.f;
      myx[1] = bxv*myx[1] + axv*d; u2 = d + myx[1];
      vy_[1] += dtb_[1]*(u1+u2);
      d = (S[1][sr+1][tx] - S[1][sr][tx]) * INVD;            // gy<255 always
      mxyy[1] = byv[1]*mxyy[1] + ayv[1]*d; u3 = d + mxyy[1];
      d = xp_ok ? (S[2][sr][txp] - S[2][sr][tx]) * INVD : 0.f;
      mxx[1] = bxv*mxx[1] + axv*d; u4 = d + mxx[1];
      vx_[1] += dtb_[1]*(u3+u4);
      if (sk0 == 1) vy_[1] += a0*dtb_[1];
      if (sk1 == 1) vy_[1] += a1*dtb_[1];
      V[0][ty+2][tx] = vy_[1];
      V[1][ty+2][tx] = vx_[1];
    }

    // ========== spin: neighbors completed step t-1 (overlapped above) ==========
    if (t > 0) {
      const unsigned tgt = (unsigned)t;
      if (hasUp) { const unsigned int* f = &flags[(blk-1)*16];
        while (__hip_atomic_load(f, __ATOMIC_RELAXED, __HIP_MEMORY_SCOPE_AGENT) < tgt) {} }
      if (hasDn) { const unsigned int* f = &flags[(blk+1)*16];
        while (__hip_atomic_load(f, __ATOMIC_RELAXED, __HIP_MEMORY_SCOPE_AGENT) < tgt) {} }
    }
    asm volatile("" ::: "memory");   // no load hoisting above the spin

    const int pr = (t - 1) & 1;      // parity of neighbor data (t>0 only)
    const float* up_sp = stage + (size_t)(pr*NBLK + (hasUp ? blk-1 : blk))*STAGE_BLK;
    const float* dn_sp = stage + (size_t)(pr*NBLK + (hasDn ? blk+1 : blk))*STAGE_BLK;

    // ========== A-boundary (register halo ingest) ==========
    if (ty == 0) {
      // k=0: gy = lo-1 (halo replica; valid iff hasUp)
      if (hasUp) {
        float syy2=0.f, syy3=0.f, sxy3t=0.f, sxy3m=0.f, sxx3t=0.f, sxx3p=0.f;
        if (t > 0) {
          syy2  = ald(up_sp + (0*4+2)*NXr + tx);
          syy3  = ald(up_sp + (0*4+3)*NXr + tx);
          sxy3t = ald(up_sp + (1*4+3)*NXr + tx);
          sxy3m = ald(up_sp + (1*4+3)*NXr + txm);
          sxx3t = ald(up_sp + (2*4+3)*NXr + tx);
          sxx3p = ald(up_sp + (2*4+3)*NXr + txp);
        }
        float d, u1, u2, u3, u4;
        d = (syy3 - syy2) * INVD;                            // gy-1 >= 2
        myy[0] = byv[0]*myy[0] + ayv[0]*d; u1 = d + myy[0];
        d = xm_ok ? (sxy3t - sxy3m) * INVD : 0.f;
        myx[0] = bxv*myx[0] + axv*d; u2 = d + myx[0];
        vy_[0] += dtb_[0]*(u1+u2);
        d = (S[1][0][tx] - sxy3t) * INVD;                    // dfy: sxy(lo)-sxy(lo-1)
        mxyy[0] = byv[0]*mxyy[0] + ayv[0]*d; u3 = d + mxyy[0];
        d = xp_ok ? (sxx3p - sxx3t) * INVD : 0.f;
        mxx[0] = bxv*mxx[0] + axv*d; u4 = d + mxx[0];
        vx_[0] += dtb_[0]*(u3+u4);
        if (sk0 == 0) vy_[0] += a0*dtb_[0];
        if (sk1 == 0) vy_[0] += a1*dtb_[0];
        V[0][0][tx] = vy_[0]; V[1][0][tx] = vx_[0];
      }
      // k=2: gy = lo+3 (own bottom row; always valid)
      {
        float sxy4t = (hasDn && t > 0) ? ald(dn_sp + (1*4+0)*NXr + tx) : 0.f;
        float d, u1, u2, u3, u4;
        d = (S[0][3][tx] - S[0][2][tx]) * INVD;
        myy[2] = byv[2]*myy[2] + ayv[2]*d; u1 = d + myy[2];
        d = xm_ok ? (S[1][3][tx] - S[1][3][txm]) * INVD : 0.f;
        myx[2] = bxv*myx[2] + axv*d; u2 = d + myx[2];
        vy_[2] += dtb_[2]*(u1+u2);
        d = hasDn ? (sxy4t - S[1][3][tx]) * INVD : 0.f;      // gy==255 only bi==63
        mxyy[2] = byv[2]*mxyy[2] + ayv[2]*d; u3 = d + mxyy[2];
        d = xp_ok ? (S[2][3][txp] - S[2][3][tx]) * INVD : 0.f;
        mxx[2] = bxv*mxx[2] + axv*d; u4 = d + mxx[2];
        vx_[2] += dtb_[2]*(u3+u4);
        if (sk0 == 2) vy_[2] += a0*dtb_[2];
        if (sk1 == 2) vy_[2] += a1*dtb_[2];
        V[0][4][tx] = vy_[2]; V[1][4][tx] = vx_[2];
      }
    } else {
      // k=0: gy = lo (own top row; always valid)
      {
        float syyU = (hasUp && t > 0) ? ald(up_sp + (0*4+3)*NXr + tx) : 0.f;
        float d, u1, u2, u3, u4;
        d = hasUp ? (S[0][0][tx] - syyU) * INVD : 0.f;       // gy==0 only bi==0
        myy[0] = byv[0]*myy[0] + ayv[0]*d; u1 = d + myy[0];
        d = xm_ok ? (S[1][0][tx] - S[1][0][txm]) * INVD : 0.f;
        myx[0] = bxv*myx[0] + axv*d; u2 = d + myx[0];
        vy_[0] += dtb_[0]*(u1+u2);
        d = (S[1][1][tx] - S[1][0][tx]) * INVD;
        mxyy[0] = byv[0]*mxyy[0] + ayv[0]*d; u3 = d + mxyy[0];
        d = xp_ok ? (S[2][0][txp] - S[2][0][tx]) * INVD : 0.f;
        mxx[0] = bxv*mxx[0] + axv*d; u4 = d + mxx[0];
        vx_[0] += dtb_[0]*(u3+u4);
        if (sk0 == 0) vy_[0] += a0*dtb_[0];
        if (sk1 == 0) vy_[0] += a1*dtb_[0];
        V[0][1][tx] = vy_[0]; V[1][1][tx] = vx_[0];
      }
      // k=2: gy = lo+4 (halo replica; valid iff hasDn)
      if (hasDn) {
        float syyD0=0.f, sxyD0t=0.f, sxyD0m=0.f, sxyD1t=0.f, sxxD0t=0.f, sxxD0p=0.f;
        if (t > 0) {
          syyD0  = ald(dn_sp + (0*4+0)*NXr + tx);
          sxyD0t = ald(dn_sp + (1*4+0)*NXr + tx);
          sxyD0m = ald(dn_sp + (1*4+0)*NXr + txm);
          sxyD1t = ald(dn_sp + (1*4+1)*NXr + tx);
          sxxD0t = ald(dn_sp + (2*4+0)*NXr + tx);
          sxxD0p = ald(dn_sp + (2*4+0)*NXr + txp);
        }
        float d, u1, u2, u3, u4;
        d = (syyD0 - S[0][3][tx]) * INVD;                    // gy-1 = lo+3 own
        myy[2] = byv[2]*myy[2] + ayv[2]*d; u1 = d + myy[2];
        d = xm_ok ? (sxyD0t - sxyD0m) * INVD : 0.f;
        myx[2] = bxv*myx[2] + axv*d; u2 = d + myx[2];
        vy_[2] += dtb_[2]*(u1+u2);
        d = (sxyD1t - sxyD0t) * INVD;                        // gy <= 252
        mxyy[2] = byv[2]*mxyy[2] + ayv[2]*d; u3 = d + mxyy[2];
        d = xp_ok ? (sxxD0p - sxxD0t) * INVD : 0.f;
        mxx[2] = bxv*mxx[2] + axv*d; u4 = d + mxx[2];
        vx_[2] += dtb_[2]*(u3+u4);
        if (sk0 == 2) vy_[2] += a0*dtb_[2];
        if (sk1 == 2) vy_[2] += a1*dtb_[2];
        V[0][5][tx] = vy_[2]; V[1][5][tx] = vx_[2];
      }
    }

    // ========== recording (own cells, post-injection) ==========
    if (recA) {
      const float v = ty ? vy_[0] : vy_[1];
      unsigned long long m = mA0; while (m) { int i = __ffsll((long long)m)-1; m &= m-1; out[i*NTr + t] = v; }
      m = mA1; while (m) { int i = __ffsll((long long)m)-1; m &= m-1; out[(i+64)*NTr + t] = v; }
    }
    if (recB) {
      const float v = ty ? vy_[1] : vy_[2];
      unsigned long long m = mB0; while (m) { int i = __ffsll((long long)m)-1; m &= m-1; out[i*NTr + t] = v; }
      m = mB1; while (m) { int i = __ffsll((long long)m)-1; m &= m-1; out[(i+64)*NTr + t] = v; }
    }

    __syncthreads();   // all V rows visible

    // ========== B: stress on own 4 rows ==========
    float* sp = stage + (size_t)((t & 1)*NBLK + blk)*STAGE_BLK;
    #pragma unroll
    for (int j = 0; j < 2; ++j) {
      const int gy = lo + ty + 2*j;
      const int vr = ty + 2*j + 1;
      float d, u5, u6, u7, u8;
      d = (gy < NYr-1) ? (V[0][vr+1][tx] - V[0][vr][tx]) * INVD : 0.f;  // dfy(vy)
      mvyy[j] = bys[j]*mvyy[j] + ays[j]*d; u5 = d + mvyy[j];
      d = xm_ok ? (V[1][vr][tx] - V[1][vr][txm]) * INVD : 0.f;          // dbx(vx)
      mvxx[j] = bxv*mvxx[j] + axv*d; u6 = d + mvxx[j];
      syy_[j] += DTv*(l2mv[j]*u5 + lamv[j]*u6);
      sxx_[j] += DTv*(lamv[j]*u5 + l2mv[j]*u6);
      d = xm_ok ? (V[0][vr][tx] - V[0][vr][txm]) * INVD : 0.f;          // dbx(vy)
      mvyx[j] = bxv*mvyx[j] + axv*d; u7 = d + mvyx[j];
      d = (gy > 0) ? (V[1][vr][tx] - V[1][vr-1][tx]) * INVD : 0.f;      // dby(vx)
      mvxy[j] = bys[j]*mvxy[j] + ays[j]*d; u8 = d + mvxy[j];
      sxy_[j] += DTv*muv[j]*(u7 + u8);
      const int r = ty + 2*j;
      S[0][r][tx] = syy_[j]; S[1][r][tx] = sxy_[j]; S[2][r][tx] = sxx_[j];
      ast(sp + (0*4+r)*NXr + tx, syy_[j]);
      ast(sp + (1*4+r)*NXr + tx, sxy_[j]);
      ast(sp + (2*4+r)*NXr + tx, sxx_[j]);
    }
    __syncthreads();   // LDS visible + stage stores vmcnt-drained
    if (tid == 0)
      __hip_atomic_store(&flags[blk*16], (unsigned)(t+1),
                         __ATOMIC_RELAXED, __HIP_MEMORY_SCOPE_AGENT);
  }
}

extern "C" void kernel_launch(void* const* d_in, const int* in_sizes, int n_in,
                              void* d_out, int out_size, void* d_ws, size_t ws_size,
                              hipStream_t stream) {
  const float* lamb    = (const float*)d_in[0];
  const float* mu      = (const float*)d_in[1];
  const float* buoy    = (const float*)d_in[2];
  const float* amps    = (const float*)d_in[3];
  const int*   src_loc = (const int*)d_in[4];
  const int*   rec_loc = (const int*)d_in[5];
  float* out = (float*)d_out;
  float* ws  = (float*)d_ws;

  // flags must start at 0 (monotonic within one launch)
  hipMemsetAsync(ws + FLAG_OFF, 0, NBLK*16*sizeof(unsigned int), stream);

  hipLaunchKernelGGL(setup_kernel, dim3(1), dim3(256), 0, stream,
                     lamb, mu, buoy, ws + COEF_OFF);

  void* args[] = { (void*)&lamb, (void*)&mu, (void*)&buoy, (void*)&amps,
                   (void*)&src_loc, (void*)&rec_loc, (void*)&ws, (void*)&out };
  hipLaunchCooperativeKernel((void*)elastic4, dim3(NBLK), dim3(512),
                             args, 0, stream);
}

// Round 6
// 671.633 us; speedup vs baseline: 11.8113x; 1.1358x over previous
//
#include <hip/hip_runtime.h>

#define NYr 256
#define NXr 256
#define NTr 256
#define NBr 2
#define NSRCr 2
#define NRECr 64
#define NBLK 128           // 2 batches x 64 blocks, 4 rows each
#define DTv 0.0005f
#define INVD 0.2f

// workspace: coef (1024 f), then 8B-aligned tag region [2 par][128 blk][8 entry][256] u64
#define COEF_OFF 0
#define TAG_F_OFF 1024                 // byte offset 4096 (8B aligned)
#define TBLK 2048                      // u64 per block slot (8*256)
// entries: 0=syy r0, 1=sxy r0, 2=sxy r1, 3=sxx r0   (consumed by UP neighbor)
//          4=syy r2, 5=syy r3, 6=sxy r3, 7=sxx r3   (consumed by DOWN neighbor)

__device__ __forceinline__ unsigned long long tld(const unsigned long long* p) {
  return __hip_atomic_load(p, __ATOMIC_RELAXED, __HIP_MEMORY_SCOPE_AGENT);
}
__device__ __forceinline__ void tst(unsigned long long* p, float v, unsigned tag) {
  unsigned long long u = ((unsigned long long)tag << 32) | (unsigned long long)__float_as_uint(v);
  __hip_atomic_store(p, u, __ATOMIC_RELAXED, __HIP_MEMORY_SCOPE_AGENT);
}
#define TVAL(x) __uint_as_float((unsigned)(x))
#define TTAG(x) ((unsigned)((x) >> 32))

__global__ __launch_bounds__(256) void setup_kernel(
    const float* __restrict__ lamb, const float* __restrict__ mu,
    const float* __restrict__ buoy, float* __restrict__ coef)
{
  __shared__ float red[256];
  const int tid = threadIdx.x;
  float m = 0.0f;
  for (int i = tid; i < NYr*NXr; i += 256)
    m = fmaxf(m, sqrtf((lamb[i] + 2.0f*mu[i]) * buoy[i]));
  red[tid] = m;
  __syncthreads();
  for (int s = 128; s > 0; s >>= 1) {
    if (tid < s) red[tid] = fmaxf(red[tid], red[tid+s]);
    __syncthreads();
  }
  const float maxv = red[0];

  const float i_f = (float)tid;
  const float w = 20.0f;
  float f1 = fminf(fmaxf((w - i_f) * (1.0f/w), 0.0f), 1.0f);
  float f2 = fminf(fmaxf((i_f - (256.0f - 1.0f - w)) * (1.0f/w), 0.0f), 1.0f);
  float frac = fmaxf(f1, f2);
  float sigma_max = 3.0f * maxv * 6.907755278982137f / (2.0f * w * 5.0f);
  float sigma = sigma_max * frac * frac;
  float alpha = 3.14159265358979323f * 25.0f * (1.0f - frac);
  float bc = expf(-(sigma + alpha) * 0.0005f);
  float ac = sigma / (sigma + alpha + 1e-9f) * (bc - 1.0f);
  coef[tid]       = ac;  // ay
  coef[256 + tid] = bc;  // by
  coef[512 + tid] = ac;  // ax
  coef[768 + tid] = bc;  // bx
}

__global__ __launch_bounds__(512) void elastic_tag(
    const float* __restrict__ lamb_g, const float* __restrict__ mu_g,
    const float* __restrict__ buoy_g, const float* __restrict__ amps,
    const int* __restrict__ src_loc, const int* __restrict__ rec_loc,
    float* __restrict__ ws, float* __restrict__ out)
{
  __shared__ float S[3][4][NXr];   // own stress rows gy = lo..lo+3
  __shared__ float V[2][6][NXr];   // velocity rows gy = lo-1..lo+4

  const int blk = blockIdx.x;
  const int b = blk >> 6, bi = blk & 63;
  const int tid = threadIdx.x;
  const int ty = tid >> 8, tx = tid & 255;   // ty is wave-uniform
  const int lo = bi << 2;
  const bool hasUp = bi > 0, hasDn = bi < 63;

  const float* coef = ws + COEF_OFF;
  unsigned long long* tagb = (unsigned long long*)(ws + TAG_F_OFF);

  const int txm = tx ? tx-1 : 0;
  const int txp = (tx < 255) ? tx+1 : 255;
  const bool xm_ok = tx > 0, xp_ok = tx < 255;
  const float axv = coef[512+tx], bxv = coef[768+tx];

  // ---- velocity cells k=0..2: gy = lo-1+ty+2k ----
  float vy_[3], vx_[3], myy[3], myx[3], mxyy[3], mxx[3];
  float dtb_[3], ayv[3], byv[3];
  #pragma unroll
  for (int k = 0; k < 3; ++k) {
    const int gy = lo - 1 + ty + 2*k;
    const bool ok = (gy >= 0) && (gy < NYr);
    const int gyc = ok ? gy : 0;
    dtb_[k] = ok ? DTv * buoy_g[gyc*NXr + tx] : 0.f;
    ayv[k]  = ok ? coef[gyc] : 0.f;
    byv[k]  = ok ? coef[256 + gyc] : 1.f;
    vy_[k] = vx_[k] = myy[k] = myx[k] = mxyy[k] = mxx[k] = 0.f;
  }
  // ---- stress cells j=0,1: gy = lo+ty+2j (always in-grid) ----
  float syy_[2], sxy_[2], sxx_[2], mvyy[2], mvxx[2], mvyx[2], mvxy[2];
  float lamv[2], muv[2], l2mv[2], ays[2], bys[2];
  #pragma unroll
  for (int j = 0; j < 2; ++j) {
    const int gy = lo + ty + 2*j;
    lamv[j] = lamb_g[gy*NXr + tx]; muv[j] = mu_g[gy*NXr + tx];
    l2mv[j] = lamv[j] + 2.f*muv[j];
    ays[j] = coef[gy]; bys[j] = coef[256 + gy];
    syy_[j] = sxy_[j] = sxx_[j] = 0.f;
    mvyy[j] = mvxx[j] = mvyx[j] = mvxy[j] = 0.f;
  }

  // ---- sources (halo replicas inject too, consistently) ----
  int sk0 = -1, sk1 = -1; int so0 = 0, so1 = 0;
  for (int i = 0; i < NBr*NSRCr; ++i) {
    const int sb = i >> 1, sy = src_loc[2*i], sx = src_loc[2*i+1];
    if (sb == b && sx == tx) {
      #pragma unroll
      for (int k = 0; k < 3; ++k) {
        const int gy = lo - 1 + ty + 2*k;
        if (gy == sy) { if (sk0 < 0) { sk0 = k; so0 = i*NTr; } else { sk1 = k; so1 = i*NTr; } }
      }
    }
  }
  // ---- receivers: own cells only ----
  const int gyA = ty ? lo     : lo + 1;
  const int gyB = ty ? lo + 2 : lo + 3;
  unsigned long long mA0=0, mA1=0, mB0=0, mB1=0;
  for (int i = 0; i < NBr*NRECr; ++i) {
    const int rb = i >> 6, ry = rec_loc[2*i], rx = rec_loc[2*i+1];
    if (rb == b && rx == tx) {
      if (ry == gyA) { if (i < 64) mA0 |= 1ull<<i; else mA1 |= 1ull<<(i-64); }
      if (ry == gyB) { if (i < 64) mB0 |= 1ull<<i; else mB1 |= 1ull<<(i-64); }
    }
  }
  const bool recA = (mA0|mA1) != 0ull, recB = (mB0|mB1) != 0ull;

  // ---- zero LDS ----
  { float* p = &S[0][0][0]; for (int i = tid; i < 3*4*NXr; i += 512) p[i] = 0.f;
    float* q = &V[0][0][0]; for (int i = tid; i < 2*6*NXr; i += 512) q[i] = 0.f; }
  __syncthreads();

  for (int t = 0; t < NTr; ++t) {
    // amps prefetch (issued early)
    float a0 = 0.f, a1 = 0.f;
    if (sk0 >= 0) a0 = amps[so0 + t];
    if (sk1 >= 0) a1 = amps[so1 + t];

    // ========== A-interior: k=1, gy = lo+1+ty (no remote deps) ==========
    {
      const int sr = 1 + ty;
      float d, u1, u2, u3, u4;
      d = (S[0][sr][tx] - S[0][sr-1][tx]) * INVD;
      myy[1] = byv[1]*myy[1] + ayv[1]*d; u1 = d + myy[1];
      d = xm_ok ? (S[1][sr][tx] - S[1][sr][txm]) * INVD : 0.f;
      myx[1] = bxv*myx[1] + axv*d; u2 = d + myx[1];
      vy_[1] += dtb_[1]*(u1+u2);
      d = (S[1][sr+1][tx] - S[1][sr][tx]) * INVD;
      mxyy[1] = byv[1]*mxyy[1] + ayv[1]*d; u3 = d + mxyy[1];
      d = xp_ok ? (S[2][sr][txp] - S[2][sr][tx]) * INVD : 0.f;
      mxx[1] = bxv*mxx[1] + axv*d; u4 = d + mxx[1];
      vx_[1] += dtb_[1]*(u3+u4);
      if (sk0 == 1) vy_[1] += a0*dtb_[1];
      if (sk1 == 1) vy_[1] += a1*dtb_[1];
      V[0][ty+2][tx] = vy_[1];
      V[1][ty+2][tx] = vx_[1];
    }

    // ========== tagged remote ingest (poll; value+tag in one 8B word) ==========
    unsigned long long u4w=0, u5w=0, u6w=0, u6mw=0, u7w=0, u7pw=0;
    unsigned long long d0w=0, d1w=0, d1mw=0, d2w=0, d3w=0, d3pw=0;
    if (t > 0) {
      const size_t pslot = (size_t)((t-1)&1)*NBLK;
      const unsigned long long* up = tagb + (pslot + (hasUp ? blk-1 : blk))*TBLK;
      const unsigned long long* dn = tagb + (pslot + (hasDn ? blk+1 : blk))*TBLK;
      const unsigned want = (unsigned)t;
      if (ty == 0) {
        for (;;) {
          u4w = tld(up+4*256+tx); u5w = tld(up+5*256+tx); u6w = tld(up+6*256+tx);
          u6mw = tld(up+6*256+txm); u7w = tld(up+7*256+tx); u7pw = tld(up+7*256+txp);
          d1w = tld(dn+1*256+tx);
          const bool okU = !hasUp || (TTAG(u4w)==want && TTAG(u5w)==want && TTAG(u6w)==want &&
                                      TTAG(u6mw)==want && TTAG(u7w)==want && TTAG(u7pw)==want);
          const bool okD = !hasDn || (TTAG(d1w)==want);
          if (okU && okD) break;
        }
      } else {
        for (;;) {
          u5w = tld(up+5*256+tx);
          d0w = tld(dn+0*256+tx); d1w = tld(dn+1*256+tx); d1mw = tld(dn+1*256+txm);
          d2w = tld(dn+2*256+tx); d3w = tld(dn+3*256+tx); d3pw = tld(dn+3*256+txp);
          const bool okU = !hasUp || (TTAG(u5w)==want);
          const bool okD = !hasDn || (TTAG(d0w)==want && TTAG(d1w)==want && TTAG(d1mw)==want &&
                                      TTAG(d2w)==want && TTAG(d3w)==want && TTAG(d3pw)==want);
          if (okU && okD) break;
        }
      }
    }

    // ========== A-boundary ==========
    if (ty == 0) {
      // k=0: gy = lo-1 (halo replica; valid iff hasUp)
      if (hasUp) {
        const float syy2 = TVAL(u4w), syy3 = TVAL(u5w);
        const float sxy3t = TVAL(u6w), sxy3m = TVAL(u6mw);
        const float sxx3t = TVAL(u7w), sxx3p = TVAL(u7pw);
        float d, u1, u2, u3, u4;
        d = (syy3 - syy2) * INVD;
        myy[0] = byv[0]*myy[0] + ayv[0]*d; u1 = d + myy[0];
        d = xm_ok ? (sxy3t - sxy3m) * INVD : 0.f;
        myx[0] = bxv*myx[0] + axv*d; u2 = d + myx[0];
        vy_[0] += dtb_[0]*(u1+u2);
        d = (S[1][0][tx] - sxy3t) * INVD;
        mxyy[0] = byv[0]*mxyy[0] + ayv[0]*d; u3 = d + mxyy[0];
        d = xp_ok ? (sxx3p - sxx3t) * INVD : 0.f;
        mxx[0] = bxv*mxx[0] + axv*d; u4 = d + mxx[0];
        vx_[0] += dtb_[0]*(u3+u4);
        if (sk0 == 0) vy_[0] += a0*dtb_[0];
        if (sk1 == 0) vy_[0] += a1*dtb_[0];
        V[0][0][tx] = vy_[0]; V[1][0][tx] = vx_[0];
      }
      // k=2: gy = lo+3 (own bottom row)
      {
        const float sxy4t = TVAL(d1w);
        float d, u1, u2, u3, u4;
        d = (S[0][3][tx] - S[0][2][tx]) * INVD;
        myy[2] = byv[2]*myy[2] + ayv[2]*d; u1 = d + myy[2];
        d = xm_ok ? (S[1][3][tx] - S[1][3][txm]) * INVD : 0.f;
        myx[2] = bxv*myx[2] + axv*d; u2 = d + myx[2];
        vy_[2] += dtb_[2]*(u1+u2);
        d = hasDn ? (sxy4t - S[1][3][tx]) * INVD : 0.f;
        mxyy[2] = byv[2]*mxyy[2] + ayv[2]*d; u3 = d + mxyy[2];
        d = xp_ok ? (S[2][3][txp] - S[2][3][tx]) * INVD : 0.f;
        mxx[2] = bxv*mxx[2] + axv*d; u4 = d + mxx[2];
        vx_[2] += dtb_[2]*(u3+u4);
        if (sk0 == 2) vy_[2] += a0*dtb_[2];
        if (sk1 == 2) vy_[2] += a1*dtb_[2];
        V[0][4][tx] = vy_[2]; V[1][4][tx] = vx_[2];
      }
    } else {
      // k=0: gy = lo (own top row)
      {
        const float syyU = TVAL(u5w);
        float d, u1, u2, u3, u4;
        d = hasUp ? (S[0][0][tx] - syyU) * INVD : 0.f;
        myy[0] = byv[0]*myy[0] + ayv[0]*d; u1 = d + myy[0];
        d = xm_ok ? (S[1][0][tx] - S[1][0][txm]) * INVD : 0.f;
        myx[0] = bxv*myx[0] + axv*d; u2 = d + myx[0];
        vy_[0] += dtb_[0]*(u1+u2);
        d = (S[1][1][tx] - S[1][0][tx]) * INVD;
        mxyy[0] = byv[0]*mxyy[0] + ayv[0]*d; u3 = d + mxyy[0];
        d = xp_ok ? (S[2][0][txp] - S[2][0][tx]) * INVD : 0.f;
        mxx[0] = bxv*mxx[0] + axv*d; u4 = d + mxx[0];
        vx_[0] += dtb_[0]*(u3+u4);
        if (sk0 == 0) vy_[0] += a0*dtb_[0];
        if (sk1 == 0) vy_[0] += a1*dtb_[0];
        V[0][1][tx] = vy_[0]; V[1][1][tx] = vx_[0];
      }
      // k=2: gy = lo+4 (halo replica; valid iff hasDn)
      if (hasDn) {
        const float syyD0 = TVAL(d0w), sxyD0t = TVAL(d1w), sxyD0m = TVAL(d1mw);
        const float sxyD1t = TVAL(d2w), sxxD0t = TVAL(d3w), sxxD0p = TVAL(d3pw);
        float d, u1, u2, u3, u4;
        d = (syyD0 - S[0][3][tx]) * INVD;
        myy[2] = byv[2]*myy[2] + ayv[2]*d; u1 = d + myy[2];
        d = xm_ok ? (sxyD0t - sxyD0m) * INVD : 0.f;
        myx[2] = bxv*myx[2] + axv*d; u2 = d + myx[2];
        vy_[2] += dtb_[2]*(u1+u2);
        d = (sxyD1t - sxyD0t) * INVD;
        mxyy[2] = byv[2]*mxyy[2] + ayv[2]*d; u3 = d + mxyy[2];
        d = xp_ok ? (sxxD0p - sxxD0t) * INVD : 0.f;
        mxx[2] = bxv*mxx[2] + axv*d; u4 = d + mxx[2];
        vx_[2] += dtb_[2]*(u3+u4);
        if (sk0 == 2) vy_[2] += a0*dtb_[2];
        if (sk1 == 2) vy_[2] += a1*dtb_[2];
        V[0][5][tx] = vy_[2]; V[1][5][tx] = vx_[2];
      }
    }

    // ========== recording (own cells, post-injection) ==========
    if (recA) {
      const float v = ty ? vy_[0] : vy_[1];
      unsigned long long m = mA0; while (m) { int i = __ffsll((long long)m)-1; m &= m-1; out[i*NTr + t] = v; }
      m = mA1; while (m) { int i = __ffsll((long long)m)-1; m &= m-1; out[(i+64)*NTr + t] = v; }
    }
    if (recB) {
      const float v = ty ? vy_[1] : vy_[2];
      unsigned long long m = mB0; while (m) { int i = __ffsll((long long)m)-1; m &= m-1; out[i*NTr + t] = v; }
      m = mB1; while (m) { int i = __ffsll((long long)m)-1; m &= m-1; out[(i+64)*NTr + t] = v; }
    }

    __syncthreads();   // all V rows visible

    // ========== B: stress on own 4 rows; tag-store boundary values ASAP ==========
    unsigned long long* my = tagb + ((size_t)(t&1)*NBLK + blk)*TBLK;
    const unsigned wtag = (unsigned)(t + 1);
    #pragma unroll
    for (int j = 0; j < 2; ++j) {
      const int gy = lo + ty + 2*j;
      const int vr = ty + 2*j + 1;
      float d, u5, u6, u7, u8;
      d = (gy < NYr-1) ? (V[0][vr+1][tx] - V[0][vr][tx]) * INVD : 0.f;  // dfy(vy)
      mvyy[j] = bys[j]*mvyy[j] + ays[j]*d; u5 = d + mvyy[j];
      d = xm_ok ? (V[1][vr][tx] - V[1][vr][txm]) * INVD : 0.f;          // dbx(vx)
      mvxx[j] = bxv*mvxx[j] + axv*d; u6 = d + mvxx[j];
      syy_[j] += DTv*(l2mv[j]*u5 + lamv[j]*u6);
      sxx_[j] += DTv*(lamv[j]*u5 + l2mv[j]*u6);
      d = xm_ok ? (V[0][vr][tx] - V[0][vr][txm]) * INVD : 0.f;          // dbx(vy)
      mvyx[j] = bxv*mvyx[j] + axv*d; u7 = d + mvyx[j];
      d = (gy > 0) ? (V[1][vr][tx] - V[1][vr-1][tx]) * INVD : 0.f;      // dby(vx)
      mvxy[j] = bys[j]*mvxy[j] + ays[j]*d; u8 = d + mvxy[j];
      sxy_[j] += DTv*muv[j]*(u7 + u8);
      const int r = ty + 2*j;
      // tagged stores first (they're on the neighbor's critical path)
      if (r == 0) {
        tst(my + 0*256 + tx, syy_[j], wtag);
        tst(my + 1*256 + tx, sxy_[j], wtag);
        tst(my + 3*256 + tx, sxx_[j], wtag);
      } else if (r == 1) {
        tst(my + 2*256 + tx, sxy_[j], wtag);
      } else if (r == 2) {
        tst(my + 4*256 + tx, syy_[j], wtag);
      } else {
        tst(my + 5*256 + tx, syy_[j], wtag);
        tst(my + 6*256 + tx, sxy_[j], wtag);
        tst(my + 7*256 + tx, sxx_[j], wtag);
      }
      S[0][r][tx] = syy_[j]; S[1][r][tx] = sxy_[j]; S[2][r][tx] = sxx_[j];
    }
    __syncthreads();   // S rows visible for next step's A-interior
  }
}

extern "C" void kernel_launch(void* const* d_in, const int* in_sizes, int n_in,
                              void* d_out, int out_size, void* d_ws, size_t ws_size,
                              hipStream_t stream) {
  const float* lamb    = (const float*)d_in[0];
  const float* mu      = (const float*)d_in[1];
  const float* buoy    = (const float*)d_in[2];
  const float* amps    = (const float*)d_in[3];
  const int*   src_loc = (const int*)d_in[4];
  const int*   rec_loc = (const int*)d_in[5];
  float* out = (float*)d_out;
  float* ws  = (float*)d_ws;

  // tag region must start at 0 every launch (tags 1..256 within one run)
  hipMemsetAsync((char*)ws + TAG_F_OFF*sizeof(float), 0,
                 (size_t)2*NBLK*TBLK*sizeof(unsigned long long), stream);

  hipLaunchKernelGGL(setup_kernel, dim3(1), dim3(256), 0, stream,
                     lamb, mu, buoy, ws + COEF_OFF);

  void* args[] = { (void*)&lamb, (void*)&mu, (void*)&buoy, (void*)&amps,
                   (void*)&src_loc, (void*)&rec_loc, (void*)&ws, (void*)&out };
  hipLaunchCooperativeKernel((void*)elastic_tag, dim3(NBLK), dim3(512),
                             args, 0, stream);
}

// Round 7
// 663.886 us; speedup vs baseline: 11.9492x; 1.0117x over previous
//
#include <hip/hip_runtime.h>

#define NYr 256
#define NXr 256
#define NTr 256
#define NBr 2
#define NSRCr 2
#define NRECr 64
#define NBLK 128           // 2 batches x 64 blocks, 4 rows each
#define DTv 0.0005f
#define INVD 0.2f

// workspace: coef (1024 f), then 8B-aligned tag region [2 par][128 blk][8 entry][256] u64
#define COEF_OFF 0
#define TAG_F_OFF 1024                 // byte offset 4096 (8B aligned)
#define TBLK 2048                      // u64 per block slot (8*256)
// entries: 0=syy r0, 1=sxy r0, 2=sxy r1, 3=sxx r0   (consumed by UP neighbor)
//          4=syy r2, 5=syy r3, 6=sxy r3, 7=sxx r3   (consumed by DOWN neighbor)

__device__ __forceinline__ unsigned long long tld(const unsigned long long* p) {
  return __hip_atomic_load(p, __ATOMIC_RELAXED, __HIP_MEMORY_SCOPE_AGENT);
}
__device__ __forceinline__ void tst(unsigned long long* p, float v, unsigned tag) {
  unsigned long long u = ((unsigned long long)tag << 32) | (unsigned long long)__float_as_uint(v);
  __hip_atomic_store(p, u, __ATOMIC_RELAXED, __HIP_MEMORY_SCOPE_AGENT);
}
#define TVAL(x) __uint_as_float((unsigned)(x))
#define TTAG(x) ((unsigned)((x) >> 32))

__global__ __launch_bounds__(256) void setup_kernel(
    const float* __restrict__ lamb, const float* __restrict__ mu,
    const float* __restrict__ buoy, float* __restrict__ coef)
{
  __shared__ float red[256];
  const int tid = threadIdx.x;
  float m = 0.0f;
  for (int i = tid; i < NYr*NXr; i += 256)
    m = fmaxf(m, sqrtf((lamb[i] + 2.0f*mu[i]) * buoy[i]));
  red[tid] = m;
  __syncthreads();
  for (int s = 128; s > 0; s >>= 1) {
    if (tid < s) red[tid] = fmaxf(red[tid], red[tid+s]);
    __syncthreads();
  }
  const float maxv = red[0];

  const float i_f = (float)tid;
  const float w = 20.0f;
  float f1 = fminf(fmaxf((w - i_f) * (1.0f/w), 0.0f), 1.0f);
  float f2 = fminf(fmaxf((i_f - (256.0f - 1.0f - w)) * (1.0f/w), 0.0f), 1.0f);
  float frac = fmaxf(f1, f2);
  float sigma_max = 3.0f * maxv * 6.907755278982137f / (2.0f * w * 5.0f);
  float sigma = sigma_max * frac * frac;
  float alpha = 3.14159265358979323f * 25.0f * (1.0f - frac);
  float bc = expf(-(sigma + alpha) * 0.0005f);
  float ac = sigma / (sigma + alpha + 1e-9f) * (bc - 1.0f);
  coef[tid]       = ac;  // ay
  coef[256 + tid] = bc;  // by
  coef[512 + tid] = ac;  // ax
  coef[768 + tid] = bc;  // bx
}

__global__ __launch_bounds__(512) void elastic_tag2(
    const float* __restrict__ lamb_g, const float* __restrict__ mu_g,
    const float* __restrict__ buoy_g, const float* __restrict__ amps,
    const int* __restrict__ src_loc, const int* __restrict__ rec_loc,
    float* __restrict__ ws, float* __restrict__ out)
{
  __shared__ float S[3][4][NXr];   // own stress rows gy = lo..lo+3
  __shared__ float V[2][6][NXr];   // velocity rows gy = lo-1..lo+4

  const int blk = blockIdx.x;
  const int b = blk >> 6, bi = blk & 63;
  const int tid = threadIdx.x;
  const int ty = tid >> 8, tx = tid & 255;   // ty is wave-uniform
  const int lo = bi << 2;
  const bool hasUp = bi > 0, hasDn = bi < 63;

  const float* coef = ws + COEF_OFF;
  unsigned long long* tagb = (unsigned long long*)(ws + TAG_F_OFF);

  const int txm = tx ? tx-1 : 0;
  const int txp = (tx < 255) ? tx+1 : 255;
  const bool xm_ok = tx > 0, xp_ok = tx < 255;
  const float axv = coef[512+tx], bxv = coef[768+tx];

  // ---- velocity cells k=0..2: gy = lo-1+ty+2k ----
  float vy_[3], vx_[3], myy[3], myx[3], mxyy[3], mxx[3];
  float dtb_[3], ayv[3], byv[3];
  #pragma unroll
  for (int k = 0; k < 3; ++k) {
    const int gy = lo - 1 + ty + 2*k;
    const bool ok = (gy >= 0) && (gy < NYr);
    const int gyc = ok ? gy : 0;
    dtb_[k] = ok ? DTv * buoy_g[gyc*NXr + tx] : 0.f;
    ayv[k]  = ok ? coef[gyc] : 0.f;
    byv[k]  = ok ? coef[256 + gyc] : 1.f;
    vy_[k] = vx_[k] = myy[k] = myx[k] = mxyy[k] = mxx[k] = 0.f;
  }
  // ---- stress cells j=0,1: gy = lo+ty+2j (always in-grid) ----
  float syy_[2], sxy_[2], sxx_[2], mvyy[2], mvxx[2], mvyx[2], mvxy[2];
  float lamv[2], muv[2], l2mv[2], ays[2], bys[2];
  #pragma unroll
  for (int j = 0; j < 2; ++j) {
    const int gy = lo + ty + 2*j;
    lamv[j] = lamb_g[gy*NXr + tx]; muv[j] = mu_g[gy*NXr + tx];
    l2mv[j] = lamv[j] + 2.f*muv[j];
    ays[j] = coef[gy]; bys[j] = coef[256 + gy];
    syy_[j] = sxy_[j] = sxx_[j] = 0.f;
    mvyy[j] = mvxx[j] = mvyx[j] = mvxy[j] = 0.f;
  }

  // ---- sources (halo replicas inject too, consistently) ----
  int sk0 = -1, sk1 = -1; int so0 = 0, so1 = 0;
  for (int i = 0; i < NBr*NSRCr; ++i) {
    const int sb = i >> 1, sy = src_loc[2*i], sx = src_loc[2*i+1];
    if (sb == b && sx == tx) {
      #pragma unroll
      for (int k = 0; k < 3; ++k) {
        const int gy = lo - 1 + ty + 2*k;
        if (gy == sy) { if (sk0 < 0) { sk0 = k; so0 = i*NTr; } else { sk1 = k; so1 = i*NTr; } }
      }
    }
  }
  // ---- receivers: own cells only ----
  const int gyA = ty ? lo     : lo + 1;
  const int gyB = ty ? lo + 2 : lo + 3;
  unsigned long long mA0=0, mA1=0, mB0=0, mB1=0;
  for (int i = 0; i < NBr*NRECr; ++i) {
    const int rb = i >> 6, ry = rec_loc[2*i], rx = rec_loc[2*i+1];
    if (rb == b && rx == tx) {
      if (ry == gyA) { if (i < 64) mA0 |= 1ull<<i; else mA1 |= 1ull<<(i-64); }
      if (ry == gyB) { if (i < 64) mB0 |= 1ull<<i; else mB1 |= 1ull<<(i-64); }
    }
  }
  const bool recA = (mA0|mA1) != 0ull, recB = (mB0|mB1) != 0ull;

  // ---- zero LDS ----
  { float* p = &S[0][0][0]; for (int i = tid; i < 3*4*NXr; i += 512) p[i] = 0.f;
    float* q = &V[0][0][0]; for (int i = tid; i < 2*6*NXr; i += 512) q[i] = 0.f; }
  __syncthreads();

  for (int t = 0; t < NTr; ++t) {
    // amps prefetch (issued early)
    float a0 = 0.f, a1 = 0.f;
    if (sk0 >= 0) a0 = amps[so0 + t];
    if (sk1 >= 0) a1 = amps[so1 + t];

    // ========== issue FIRST tagged-load round BEFORE A-interior ==========
    unsigned long long u4w=0, u5w=0, u6w=0, u6mw=0, u7w=0, u7pw=0;
    unsigned long long d0w=0, d1w=0, d1mw=0, d2w=0, d3w=0, d3pw=0;
    const size_t pslot = (size_t)((t-1)&1)*NBLK;
    const unsigned long long* up = tagb + (pslot + (hasUp ? blk-1 : blk))*TBLK;
    const unsigned long long* dn = tagb + (pslot + (hasDn ? blk+1 : blk))*TBLK;
    if (t > 0) {
      if (ty == 0) {
        u4w = tld(up+4*256+tx); u5w = tld(up+5*256+tx); u6w = tld(up+6*256+tx);
        u6mw = tld(up+6*256+txm); u7w = tld(up+7*256+tx); u7pw = tld(up+7*256+txp);
        d1w = tld(dn+1*256+tx);
      } else {
        u5w = tld(up+5*256+tx);
        d0w = tld(dn+0*256+tx); d1w = tld(dn+1*256+tx); d1mw = tld(dn+1*256+txm);
        d2w = tld(dn+2*256+tx); d3w = tld(dn+3*256+tx); d3pw = tld(dn+3*256+txp);
      }
    }

    // ========== A-interior: k=1, gy = lo+1+ty (overlaps the load round) ==========
    {
      const int sr = 1 + ty;
      float d, u1, u2, u3, u4;
      d = (S[0][sr][tx] - S[0][sr-1][tx]) * INVD;
      myy[1] = byv[1]*myy[1] + ayv[1]*d; u1 = d + myy[1];
      d = xm_ok ? (S[1][sr][tx] - S[1][sr][txm]) * INVD : 0.f;
      myx[1] = bxv*myx[1] + axv*d; u2 = d + myx[1];
      vy_[1] += dtb_[1]*(u1+u2);
      d = (S[1][sr+1][tx] - S[1][sr][tx]) * INVD;
      mxyy[1] = byv[1]*mxyy[1] + ayv[1]*d; u3 = d + mxyy[1];
      d = xp_ok ? (S[2][sr][txp] - S[2][sr][tx]) * INVD : 0.f;
      mxx[1] = bxv*mxx[1] + axv*d; u4 = d + mxx[1];
      vx_[1] += dtb_[1]*(u3+u4);
      if (sk0 == 1) vy_[1] += a0*dtb_[1];
      if (sk1 == 1) vy_[1] += a1*dtb_[1];
      V[0][ty+2][tx] = vy_[1];
      V[1][ty+2][tx] = vx_[1];
    }

    // ========== check tags; re-poll only on miss ==========
    if (t > 0) {
      const unsigned want = (unsigned)t;
      if (ty == 0) {
        for (;;) {
          const bool okU = !hasUp || (TTAG(u4w)==want && TTAG(u5w)==want && TTAG(u6w)==want &&
                                      TTAG(u6mw)==want && TTAG(u7w)==want && TTAG(u7pw)==want);
          const bool okD = !hasDn || (TTAG(d1w)==want);
          if (okU && okD) break;
          u4w = tld(up+4*256+tx); u5w = tld(up+5*256+tx); u6w = tld(up+6*256+tx);
          u6mw = tld(up+6*256+txm); u7w = tld(up+7*256+tx); u7pw = tld(up+7*256+txp);
          d1w = tld(dn+1*256+tx);
        }
      } else {
        for (;;) {
          const bool okU = !hasUp || (TTAG(u5w)==want);
          const bool okD = !hasDn || (TTAG(d0w)==want && TTAG(d1w)==want && TTAG(d1mw)==want &&
                                      TTAG(d2w)==want && TTAG(d3w)==want && TTAG(d3pw)==want);
          if (okU && okD) break;
          u5w = tld(up+5*256+tx);
          d0w = tld(dn+0*256+tx); d1w = tld(dn+1*256+tx); d1mw = tld(dn+1*256+txm);
          d2w = tld(dn+2*256+tx); d3w = tld(dn+3*256+tx); d3pw = tld(dn+3*256+txp);
        }
      }
    }

    // ========== A-boundary ==========
    if (ty == 0) {
      // k=0: gy = lo-1 (halo replica; valid iff hasUp)
      if (hasUp) {
        const float syy2 = TVAL(u4w), syy3 = TVAL(u5w);
        const float sxy3t = TVAL(u6w), sxy3m = TVAL(u6mw);
        const float sxx3t = TVAL(u7w), sxx3p = TVAL(u7pw);
        float d, u1, u2, u3, u4;
        d = (syy3 - syy2) * INVD;
        myy[0] = byv[0]*myy[0] + ayv[0]*d; u1 = d + myy[0];
        d = xm_ok ? (sxy3t - sxy3m) * INVD : 0.f;
        myx[0] = bxv*myx[0] + axv*d; u2 = d + myx[0];
        vy_[0] += dtb_[0]*(u1+u2);
        d = (S[1][0][tx] - sxy3t) * INVD;
        mxyy[0] = byv[0]*mxyy[0] + ayv[0]*d; u3 = d + mxyy[0];
        d = xp_ok ? (sxx3p - sxx3t) * INVD : 0.f;
        mxx[0] = bxv*mxx[0] + axv*d; u4 = d + mxx[0];
        vx_[0] += dtb_[0]*(u3+u4);
        if (sk0 == 0) vy_[0] += a0*dtb_[0];
        if (sk1 == 0) vy_[0] += a1*dtb_[0];
        V[0][0][tx] = vy_[0]; V[1][0][tx] = vx_[0];
      }
      // k=2: gy = lo+3 (own bottom row)
      {
        const float sxy4t = TVAL(d1w);
        float d, u1, u2, u3, u4;
        d = (S[0][3][tx] - S[0][2][tx]) * INVD;
        myy[2] = byv[2]*myy[2] + ayv[2]*d; u1 = d + myy[2];
        d = xm_ok ? (S[1][3][tx] - S[1][3][txm]) * INVD : 0.f;
        myx[2] = bxv*myx[2] + axv*d; u2 = d + myx[2];
        vy_[2] += dtb_[2]*(u1+u2);
        d = hasDn ? (sxy4t - S[1][3][tx]) * INVD : 0.f;
        mxyy[2] = byv[2]*mxyy[2] + ayv[2]*d; u3 = d + mxyy[2];
        d = xp_ok ? (S[2][3][txp] - S[2][3][tx]) * INVD : 0.f;
        mxx[2] = bxv*mxx[2] + axv*d; u4 = d + mxx[2];
        vx_[2] += dtb_[2]*(u3+u4);
        if (sk0 == 2) vy_[2] += a0*dtb_[2];
        if (sk1 == 2) vy_[2] += a1*dtb_[2];
        V[0][4][tx] = vy_[2]; V[1][4][tx] = vx_[2];
      }
    } else {
      // k=0: gy = lo (own top row)
      {
        const float syyU = TVAL(u5w);
        float d, u1, u2, u3, u4;
        d = hasUp ? (S[0][0][tx] - syyU) * INVD : 0.f;
        myy[0] = byv[0]*myy[0] + ayv[0]*d; u1 = d + myy[0];
        d = xm_ok ? (S[1][0][tx] - S[1][0][txm]) * INVD : 0.f;
        myx[0] = bxv*myx[0] + axv*d; u2 = d + myx[0];
        vy_[0] += dtb_[0]*(u1+u2);
        d = (S[1][1][tx] - S[1][0][tx]) * INVD;
        mxyy[0] = byv[0]*mxyy[0] + ayv[0]*d; u3 = d + mxyy[0];
        d = xp_ok ? (S[2][0][txp] - S[2][0][tx]) * INVD : 0.f;
        mxx[0] = bxv*mxx[0] + axv*d; u4 = d + mxx[0];
        vx_[0] += dtb_[0]*(u3+u4);
        if (sk0 == 0) vy_[0] += a0*dtb_[0];
        if (sk1 == 0) vy_[0] += a1*dtb_[0];
        V[0][1][tx] = vy_[0]; V[1][1][tx] = vx_[0];
      }
      // k=2: gy = lo+4 (halo replica; valid iff hasDn)
      if (hasDn) {
        const float syyD0 = TVAL(d0w), sxyD0t = TVAL(d1w), sxyD0m = TVAL(d1mw);
        const float sxyD1t = TVAL(d2w), sxxD0t = TVAL(d3w), sxxD0p = TVAL(d3pw);
        float d, u1, u2, u3, u4;
        d = (syyD0 - S[0][3][tx]) * INVD;
        myy[2] = byv[2]*myy[2] + ayv[2]*d; u1 = d + myy[2];
        d = xm_ok ? (sxyD0t - sxyD0m) * INVD : 0.f;
        myx[2] = bxv*myx[2] + axv*d; u2 = d + myx[2];
        vy_[2] += dtb_[2]*(u1+u2);
        d = (sxyD1t - sxyD0t) * INVD;
        mxyy[2] = byv[2]*mxyy[2] + ayv[2]*d; u3 = d + mxyy[2];
        d = xp_ok ? (sxxD0p - sxxD0t) * INVD : 0.f;
        mxx[2] = bxv*mxx[2] + axv*d; u4 = d + mxx[2];
        vx_[2] += dtb_[2]*(u3+u4);
        if (sk0 == 2) vy_[2] += a0*dtb_[2];
        if (sk1 == 2) vy_[2] += a1*dtb_[2];
        V[0][5][tx] = vy_[2]; V[1][5][tx] = vx_[2];
      }
    }

    __syncthreads();   // all V rows visible

    // ========== B: stress on own 4 rows; tag-store boundary values ASAP ==========
    unsigned long long* my = tagb + ((size_t)(t&1)*NBLK + blk)*TBLK;
    const unsigned wtag = (unsigned)(t + 1);
    #pragma unroll
    for (int j = 0; j < 2; ++j) {
      const int gy = lo + ty + 2*j;
      const int vr = ty + 2*j + 1;
      float d, u5, u6, u7, u8;
      d = (gy < NYr-1) ? (V[0][vr+1][tx] - V[0][vr][tx]) * INVD : 0.f;  // dfy(vy)
      mvyy[j] = bys[j]*mvyy[j] + ays[j]*d; u5 = d + mvyy[j];
      d = xm_ok ? (V[1][vr][tx] - V[1][vr][txm]) * INVD : 0.f;          // dbx(vx)
      mvxx[j] = bxv*mvxx[j] + axv*d; u6 = d + mvxx[j];
      syy_[j] += DTv*(l2mv[j]*u5 + lamv[j]*u6);
      sxx_[j] += DTv*(lamv[j]*u5 + l2mv[j]*u6);
      d = xm_ok ? (V[0][vr][tx] - V[0][vr][txm]) * INVD : 0.f;          // dbx(vy)
      mvyx[j] = bxv*mvyx[j] + axv*d; u7 = d + mvyx[j];
      d = (gy > 0) ? (V[1][vr][tx] - V[1][vr-1][tx]) * INVD : 0.f;      // dby(vx)
      mvxy[j] = bys[j]*mvxy[j] + ays[j]*d; u8 = d + mvxy[j];
      sxy_[j] += DTv*muv[j]*(u7 + u8);
      const int r = ty + 2*j;
      // tagged stores first (they're on the neighbor's critical path)
      if (r == 0) {
        tst(my + 0*256 + tx, syy_[j], wtag);
        tst(my + 1*256 + tx, sxy_[j], wtag);
        tst(my + 3*256 + tx, sxx_[j], wtag);
      } else if (r == 1) {
        tst(my + 2*256 + tx, sxy_[j], wtag);
      } else if (r == 2) {
        tst(my + 4*256 + tx, syy_[j], wtag);
      } else {
        tst(my + 5*256 + tx, syy_[j], wtag);
        tst(my + 6*256 + tx, sxy_[j], wtag);
        tst(my + 7*256 + tx, sxx_[j], wtag);
      }
      S[0][r][tx] = syy_[j]; S[1][r][tx] = sxy_[j]; S[2][r][tx] = sxx_[j];
    }
    __syncthreads();   // S rows visible for next step's A-interior

    // ========== recording AFTER the barrier (off the drain path) ==========
    if (recA) {
      const float v = ty ? vy_[0] : vy_[1];
      unsigned long long m = mA0; while (m) { int i = __ffsll((long long)m)-1; m &= m-1; out[i*NTr + t] = v; }
      m = mA1; while (m) { int i = __ffsll((long long)m)-1; m &= m-1; out[(i+64)*NTr + t] = v; }
    }
    if (recB) {
      const float v = ty ? vy_[1] : vy_[2];
      unsigned long long m = mB0; while (m) { int i = __ffsll((long long)m)-1; m &= m-1; out[i*NTr + t] = v; }
      m = mB1; while (m) { int i = __ffsll((long long)m)-1; m &= m-1; out[(i+64)*NTr + t] = v; }
    }
  }
}

extern "C" void kernel_launch(void* const* d_in, const int* in_sizes, int n_in,
                              void* d_out, int out_size, void* d_ws, size_t ws_size,
                              hipStream_t stream) {
  const float* lamb    = (const float*)d_in[0];
  const float* mu      = (const float*)d_in[1];
  const float* buoy    = (const float*)d_in[2];
  const float* amps    = (const float*)d_in[3];
  const int*   src_loc = (const int*)d_in[4];
  const int*   rec_loc = (const int*)d_in[5];
  float* out = (float*)d_out;
  float* ws  = (float*)d_ws;

  // tag region must start at 0 every launch (tags 1..256 within one run)
  hipMemsetAsync((char*)ws + TAG_F_OFF*sizeof(float), 0,
                 (size_t)2*NBLK*TBLK*sizeof(unsigned long long), stream);

  hipLaunchKernelGGL(setup_kernel, dim3(1), dim3(256), 0, stream,
                     lamb, mu, buoy, ws + COEF_OFF);

  void* args[] = { (void*)&lamb, (void*)&mu, (void*)&buoy, (void*)&amps,
                   (void*)&src_loc, (void*)&rec_loc, (void*)&ws, (void*)&out };
  hipLaunchCooperativeKernel((void*)elastic_tag2, dim3(NBLK), dim3(512),
                             args, 0, stream);
}